// Round 14
// baseline (104.944 us; speedup 1.0000x reference)
//
#include <hip/hip_runtime.h>
#include <hip/hip_bf16.h>

#define NB 4096
#define DK 1024           // elements per row (fp8 row = 1024 B)
#define EPSF 1e-6f
#define QSCALE 16.0f      // fp8 pre-scale (power of 2; cancelled exactly in exp)

typedef __attribute__((ext_vector_type(8))) int   i32x8_t;
typedef __attribute__((ext_vector_type(4))) int   i32x4_t;
typedef __attribute__((ext_vector_type(4))) float f32x4_t;

// ---------------------------------------------------------------------------
// Global fp8 layout (r11-proven): for row, k:
//   p=row>>4, r=row&15, kb=k>>7, s=(k>>4)&7, b=k&15:
//   byte offset = (p*32 + kb*4)*512 + r*128 + ((s ^ (r&7))<<4) + b
// (p,kb) chunk is 2 KB contiguous; consecutive kb chunks of a panel are
// contiguous, so a BK=256 stage copies 4 KB/panel verbatim.
// ---------------------------------------------------------------------------

__device__ __forceinline__ void async16(const void* g, void* lds) {
    __builtin_amdgcn_global_load_lds(
        (const __attribute__((address_space(1))) void*)g,
        (__attribute__((address_space(3))) void*)lds, 16, 0, 0);
}

// ---------------------------------------------------------------------------
// Kernel 1: wave-per-row normalize -> fp8 e4m3 (x QSCALE) in swizzled layout;
// exact fp32 diagonal; zeroes rowsum/colsum. (r11, unchanged)
// ---------------------------------------------------------------------------
__global__ __launch_bounds__(256) void normalize_rows(
    const float* __restrict__ x, const float* __restrict__ y,
    unsigned char* __restrict__ xq, unsigned char* __restrict__ yq,
    float* __restrict__ sdiag, float* __restrict__ zerobuf)
{
    const int t = threadIdx.x;
    const int gid = blockIdx.x * 256 + t;
    if (gid < 2 * NB) zerobuf[gid] = 0.f;   // rowsum+colsum contiguous

    const int wave = t >> 6;
    const int lane = t & 63;
    const int row  = blockIdx.x * 4 + wave;

    const float4* xr = reinterpret_cast<const float4*>(x + (size_t)row * DK);
    const float4* yr = reinterpret_cast<const float4*>(y + (size_t)row * DK);

    float4 xv[4], yv[4];
    float ssx = 0.f, ssy = 0.f, sxy = 0.f;
    #pragma unroll
    for (int jj = 0; jj < 4; ++jj) {
        xv[jj] = xr[lane * 4 + jj];
        yv[jj] = yr[lane * 4 + jj];
        ssx += xv[jj].x*xv[jj].x + xv[jj].y*xv[jj].y + xv[jj].z*xv[jj].z + xv[jj].w*xv[jj].w;
        ssy += yv[jj].x*yv[jj].x + yv[jj].y*yv[jj].y + yv[jj].z*yv[jj].z + yv[jj].w*yv[jj].w;
        sxy += xv[jj].x*yv[jj].x + xv[jj].y*yv[jj].y + xv[jj].z*yv[jj].z + xv[jj].w*yv[jj].w;
    }
    #pragma unroll
    for (int off = 1; off < 64; off <<= 1) {
        ssx += __shfl_xor(ssx, off, 64);
        ssy += __shfl_xor(ssy, off, 64);
        sxy += __shfl_xor(sxy, off, 64);
    }
    const float invx = 1.0f / fmaxf(sqrtf(ssx), EPSF);
    const float invy = 1.0f / fmaxf(sqrtf(ssy), EPSF);
    const float sx = invx * QSCALE;
    const float sy = invy * QSCALE;

    i32x4_t xb, yb;
    #pragma unroll
    for (int jj = 0; jj < 4; ++jj) {
        int px = __builtin_amdgcn_cvt_pk_fp8_f32(xv[jj].x * sx, xv[jj].y * sx, 0, false);
        px     = __builtin_amdgcn_cvt_pk_fp8_f32(xv[jj].z * sx, xv[jj].w * sx, px, true);
        int py = __builtin_amdgcn_cvt_pk_fp8_f32(yv[jj].x * sy, yv[jj].y * sy, 0, false);
        py     = __builtin_amdgcn_cvt_pk_fp8_f32(yv[jj].z * sy, yv[jj].w * sy, py, true);
        xb[jj] = px;
        yb[jj] = py;
    }

    const int p = row >> 4, r = row & 15;
    const unsigned off = (unsigned)(p * 32 + (lane >> 3) * 4) * 512
                       + r * 128 + ((((lane & 7) ^ (r & 7))) << 4);
    *reinterpret_cast<i32x4_t*>(xq + off) = xb;
    *reinterpret_cast<i32x4_t*>(yq + off) = yb;

    if (lane == 0) sdiag[row] = sxy * invx * invy;
}

// ---------------------------------------------------------------------------
// Kernel 2: S' = 256 * xn*yn^T via MX-fp8, 256x256 tiles, 512 threads,
// grid 256 = 1 block/CU.  ROUND-14 EXPERIMENT: BK=256 -> 4 stages instead
// of 8. r13 measured ~13,400 cyc/stage against ~2,200 cyc of MFMA content —
// stage time is dominated by a per-stage cost that six restructures did not
// remove. Halving stage count tests the "fixed per-stage overhead" model:
// predict GEMM 44.6 -> ~22-28 us if right, unchanged if the wall is a hard
// per-CU staging rate. Single-buffered 128 KB LDS (dbuf can't fit; r11-vs-r13
// showed dbuf was worth <=3 us). Plain __syncthreads (vmcnt(0) drain).
// Per stage/wave: 16 x 1 KB DMAs (2 A-panels + 2 B-panels x 4 KB), 64 MFMAs.
// ---------------------------------------------------------------------------
__global__ __launch_bounds__(512) void gemm_exp_sums(
    const unsigned char* __restrict__ xq, const unsigned char* __restrict__ yq,
    float* __restrict__ rowsum, float* __restrict__ colsum)
{
    __shared__ __align__(16) unsigned char LDS[131072];  // A: 0-64K, B: 64K-128K

    const int t    = threadIdx.x;
    const int lane = t & 63;
    const int wave = t >> 6;        // 0..7
    const int q    = lane >> 4;
    const int l15  = lane & 15;

    const int R0 = blockIdx.y * 256;
    const int C0 = blockIdx.x * 256;
    const int wRow = (wave >> 2) * 64;   // 0 or 64 (second half at +128)
    const int wCol = (wave & 3) * 64;    // 0,64,128,192

    f32x4_t acc[2][4][4];
    #pragma unroll
    for (int hh = 0; hh < 2; hh++)
        #pragma unroll
        for (int i = 0; i < 4; i++)
            #pragma unroll
            for (int j = 0; j < 4; j++)
                acc[hh][i][j] = (f32x4_t){0.f, 0.f, 0.f, 0.f};

    // DMA sources: wave stages A panels {2w,2w+1} and B panels {2w,2w+1}.
    // Panel p: global byte base p*16384; stage s covers kb={2s,2s+1} = 4 KB
    // contiguous at + s*4096.
    const unsigned char* srcA =
        xq + (size_t)((R0 >> 4) + 2 * wave) * 16384 + lane * 16;
    const unsigned char* srcB =
        yq + (size_t)((C0 >> 4) + 2 * wave) * 16384 + lane * 16;

    const int sLo = (((2 * q)    ) ^ (l15 & 7)) << 4;
    const int sHi = (((2 * q) + 1) ^ (l15 & 7)) << 4;

    #pragma unroll 1
    for (int s = 0; s < 4; ++s) {
        __syncthreads();   // prior stage's LDS reads complete before overwrite
        #pragma unroll
        for (int pp = 0; pp < 2; ++pp) {
            #pragma unroll
            for (int h4 = 0; h4 < 4; ++h4) {
                async16(srcA + pp * 16384 + s * 4096 + h4 * 1024,
                        &LDS[(2 * wave + pp) * 4096 + h4 * 1024]);
                async16(srcB + pp * 16384 + s * 4096 + h4 * 1024,
                        &LDS[65536 + (2 * wave + pp) * 4096 + h4 * 1024]);
            }
        }
        __syncthreads();   // vmcnt(0) drain: staged data visible

        #pragma unroll
        for (int ks = 0; ks < 2; ++ks) {
            i32x8_t bfr[4];
            #pragma unroll
            for (int nt = 0; nt < 4; ++nt) {
                const unsigned char* c =
                    &LDS[65536 + ((wCol >> 4) + nt) * 4096 + ks * 2048 + l15 * 128];
                const i32x4_t lo = *reinterpret_cast<const i32x4_t*>(c + sLo);
                const i32x4_t hi = *reinterpret_cast<const i32x4_t*>(c + sHi);
                bfr[nt][0] = lo[0]; bfr[nt][1] = lo[1]; bfr[nt][2] = lo[2]; bfr[nt][3] = lo[3];
                bfr[nt][4] = hi[0]; bfr[nt][5] = hi[1]; bfr[nt][6] = hi[2]; bfr[nt][7] = hi[3];
            }
            #pragma unroll
            for (int hh = 0; hh < 2; ++hh) {
                #pragma unroll
                for (int mt = 0; mt < 4; ++mt) {
                    const unsigned char* c =
                        &LDS[((wRow >> 4) + hh * 8 + mt) * 4096 + ks * 2048 + l15 * 128];
                    const i32x4_t lo = *reinterpret_cast<const i32x4_t*>(c + sLo);
                    const i32x4_t hi = *reinterpret_cast<const i32x4_t*>(c + sHi);
                    i32x8_t af;
                    af[0] = lo[0]; af[1] = lo[1]; af[2] = lo[2]; af[3] = lo[3];
                    af[4] = hi[0]; af[5] = hi[1]; af[6] = hi[2]; af[7] = hi[3];
                    #pragma unroll
                    for (int nt = 0; nt < 4; ++nt)
                        acc[hh][mt][nt] = __builtin_amdgcn_mfma_scale_f32_16x16x128_f8f6f4(
                            af, bfr[nt], acc[hh][mt][nt],
                            0, 0,                       // cbsz/blgp = fp8 e4m3
                            0, 0x7F7F7F7F,              // A scales: 2^0
                            0, 0x7F7F7F7F);             // B scales: 2^0
                }
            }
        }
    }

    // Epilogue: E = exp(S/TAU); acc holds 256*S -> exp2(acc / (256*TAU*ln2)).
    const float kScale = (float)(1.0 / (256.0 * 0.07 * 0.6931471805599453));
    float csum[4] = {0.f, 0.f, 0.f, 0.f};
    #pragma unroll
    for (int hh = 0; hh < 2; ++hh) {
        #pragma unroll
        for (int mt = 0; mt < 4; ++mt) {
            float rsum[4] = {0.f, 0.f, 0.f, 0.f};
            #pragma unroll
            for (int nt = 0; nt < 4; ++nt) {
                #pragma unroll
                for (int r = 0; r < 4; ++r) {
                    const float e = exp2f(acc[hh][mt][nt][r] * kScale);
                    rsum[r]  += e;
                    csum[nt] += e;
                }
            }
            #pragma unroll
            for (int r = 0; r < 4; ++r) {
                float v = rsum[r];
                v += __shfl_xor(v, 1, 64);
                v += __shfl_xor(v, 2, 64);
                v += __shfl_xor(v, 4, 64);
                v += __shfl_xor(v, 8, 64);
                if (l15 == 0)
                    atomicAdd(&rowsum[R0 + wRow + hh * 128 + mt * 16 + q * 4 + r], v);
            }
        }
    }
    #pragma unroll
    for (int nt = 0; nt < 4; ++nt) {
        float v = csum[nt];
        v += __shfl_xor(v, 16, 64);
        v += __shfl_xor(v, 32, 64);
        if (lane < 16)
            atomicAdd(&colsum[C0 + wCol + nt * 16 + l15], v);
    }
}

// ---------------------------------------------------------------------------
// Kernel 3: loss = -1/(2B) [ (2/TAU)*sum(sdiag) - sum(log(rowsum+extra))
//                            - sum(log(colsum+extra)) ]
// ---------------------------------------------------------------------------
__global__ __launch_bounds__(1024) void finalize(
    const float* __restrict__ rowsum, const float* __restrict__ colsum,
    const float* __restrict__ sdiag, float* __restrict__ out)
{
    const float extra = (float)(NB * 1e-6 + 1e-6);
    double local = 0.0;
    for (int i = threadIdx.x; i < NB; i += 1024) {
        local += (double)sdiag[i] * (2.0 / 0.07)
               - (double)logf(rowsum[i] + extra)
               - (double)logf(colsum[i] + extra);
    }
    #pragma unroll
    for (int off = 1; off < 64; off <<= 1)
        local += __shfl_xor(local, off, 64);
    __shared__ double dred[16];
    const int wave = threadIdx.x >> 6;
    if ((threadIdx.x & 63) == 0) dred[wave] = local;
    __syncthreads();
    if (threadIdx.x == 0) {
        double tot = 0.0;
        #pragma unroll
        for (int w = 0; w < 16; ++w) tot += dred[w];
        out[0] = (float)(tot * (-1.0 / (2.0 * NB)));
    }
}

// ---------------------------------------------------------------------------
extern "C" void kernel_launch(void* const* d_in, const int* in_sizes, int n_in,
                              void* d_out, int out_size, void* d_ws, size_t ws_size,
                              hipStream_t stream)
{
    const float* x = (const float*)d_in[0];
    const float* y = (const float*)d_in[1];
    float* out = (float*)d_out;

    char* ws = (char*)d_ws;
    unsigned char* xq = (unsigned char*)ws;                                 // 4 MB swizzled
    unsigned char* yq = (unsigned char*)(ws + (size_t)4 * 1024 * 1024);     // 4 MB swizzled
    float* rowsum = (float*)(ws + (size_t)8 * 1024 * 1024);                 // 16 KB
    float* colsum = rowsum + NB;                                            // 16 KB
    float* sdiag  = colsum + NB;                                            // 16 KB

    normalize_rows<<<NB / 4, 256, 0, stream>>>(x, y, xq, yq, sdiag, rowsum);

    dim3 grid(16, 16);
    gemm_exp_sums<<<grid, 512, 0, stream>>>(xq, yq, rowsum, colsum);

    finalize<<<1, 1024, 0, stream>>>(rowsum, colsum, sdiag, out);
}

// Round 15
// 99.693 us; speedup vs baseline: 1.0527x; 1.0527x over previous
//
#include <hip/hip_runtime.h>
#include <hip/hip_bf16.h>

#define NB 4096
#define DK 1024
#define EPSF 1e-6f
#define QS 32.0f          // fp4 pre-scale 2^5: normalized entries sigma=1/32 -> sigma=1

typedef __attribute__((ext_vector_type(8))) int   i32x8_t;
typedef __attribute__((ext_vector_type(4))) int   i32x4_t;
typedef __attribute__((ext_vector_type(4))) float f32x4_t;

// ---------------------------------------------------------------------------
// Global fp4 layout (r11 swizzle, halved): row,k -> p=row>>4, r=row&15,
// kb=k>>7, slot s=(k>>5)&3 (32 k / 16 B), nibble n=k&31:
//   byte offset = p*8192 + kb*1024 + r*64 + ((s^(r&3))<<4) + (n>>1), nibble n&1
// (p,kb) chunk = 1 KB contiguous -> one 64-lane x 16 B DMA.
// ---------------------------------------------------------------------------

__device__ __forceinline__ void async16(const void* g, void* lds) {
    __builtin_amdgcn_global_load_lds(
        (const __attribute__((address_space(1))) void*)g,
        (__attribute__((address_space(3))) void*)lds, 16, 0, 0);
}

// branchless e2m1 encode of a (pre-scaled) float: grid 0,.5,1,1.5,2,3,4,6.
// code 0..7 is monotone in |v|; bit3 = sign.
__device__ __forceinline__ unsigned enc4(float v) {
    const float a = fabsf(v);
    unsigned c = (a >= 0.25f) + (a >= 0.75f) + (a >= 1.25f) + (a >= 1.75f)
               + (a >= 2.5f)  + (a >= 3.5f)  + (a >= 5.0f);
    return c | ((v < 0.f) ? 8u : 0u);
}

// ---------------------------------------------------------------------------
// Kernel 1: wave-per-row normalize -> fp4 e2m1 (x32) in swizzled layout;
// exact fp32 diagonal; zeroes rowsum/colsum. Lane l owns k[16l,16l+16) ->
// 16 nibbles = 8 B, one dwordx2 store per matrix.
// ---------------------------------------------------------------------------
__global__ __launch_bounds__(256) void normalize_rows(
    const float* __restrict__ x, const float* __restrict__ y,
    unsigned char* __restrict__ xq, unsigned char* __restrict__ yq,
    float* __restrict__ sdiag, float* __restrict__ zerobuf)
{
    const int t = threadIdx.x;
    const int gid = blockIdx.x * 256 + t;
    if (gid < 2 * NB) zerobuf[gid] = 0.f;   // rowsum+colsum contiguous

    const int wave = t >> 6;
    const int lane = t & 63;
    const int row  = blockIdx.x * 4 + wave;

    const float4* xr = reinterpret_cast<const float4*>(x + (size_t)row * DK);
    const float4* yr = reinterpret_cast<const float4*>(y + (size_t)row * DK);

    float4 xv[4], yv[4];
    float ssx = 0.f, ssy = 0.f, sxy = 0.f;
    #pragma unroll
    for (int jj = 0; jj < 4; ++jj) {
        xv[jj] = xr[lane * 4 + jj];
        yv[jj] = yr[lane * 4 + jj];
        ssx += xv[jj].x*xv[jj].x + xv[jj].y*xv[jj].y + xv[jj].z*xv[jj].z + xv[jj].w*xv[jj].w;
        ssy += yv[jj].x*yv[jj].x + yv[jj].y*yv[jj].y + yv[jj].z*yv[jj].z + yv[jj].w*yv[jj].w;
        sxy += xv[jj].x*yv[jj].x + xv[jj].y*yv[jj].y + xv[jj].z*yv[jj].z + xv[jj].w*yv[jj].w;
    }
    #pragma unroll
    for (int off = 1; off < 64; off <<= 1) {
        ssx += __shfl_xor(ssx, off, 64);
        ssy += __shfl_xor(ssy, off, 64);
        sxy += __shfl_xor(sxy, off, 64);
    }
    const float invx = 1.0f / fmaxf(sqrtf(ssx), EPSF);
    const float invy = 1.0f / fmaxf(sqrtf(ssy), EPSF);
    const float sx = invx * QS;
    const float sy = invy * QS;

    // Pack 16 values -> 8 bytes: byte m = nib(j=2m) | nib(j=2m+1)<<4.
    unsigned xb[2] = {0u, 0u}, yb[2] = {0u, 0u};
    #pragma unroll
    for (int jj = 0; jj < 4; ++jj) {
        const float fx[4] = {xv[jj].x, xv[jj].y, xv[jj].z, xv[jj].w};
        const float fy[4] = {yv[jj].x, yv[jj].y, yv[jj].z, yv[jj].w};
        #pragma unroll
        for (int cc = 0; cc < 4; ++cc) {
            const int j = jj * 4 + cc;          // 0..15
            xb[j >> 3] |= enc4(fx[cc] * sx) << ((j & 7) * 4);
            yb[j >> 3] |= enc4(fy[cc] * sy) << ((j & 7) * 4);
        }
    }

    const int p = row >> 4, r = row & 15;
    const unsigned off = (unsigned)p * 8192 + (lane >> 3) * 1024 + r * 64
                       + ((((lane & 7) >> 1) ^ (r & 3)) << 4) + (lane & 1) * 8;
    *reinterpret_cast<uint2*>(xq + off) = make_uint2(xb[0], xb[1]);
    *reinterpret_cast<uint2*>(yq + off) = make_uint2(yb[0], yb[1]);

    if (lane == 0) sdiag[row] = sxy * invx * invy;
}

// ---------------------------------------------------------------------------
// Kernel 2: S' = 1024 * xn*yn^T via MX-fp4 (unit scales, cbsz=blgp=4),
// 256x256 tiles, 512 threads, grid 256 = 1 block/CU, double-buffered LDS
// (2 x 32 KB), raw s_waitcnt vmcnt(4) + raw s_barrier (r13 structure with
// halved payloads: 4 x 1 KB DMAs/wave/stage, fragment = one ds_read_b128,
// operand regs [4:7] zeroed — fp4 uses 4 VGPRs).
// ---------------------------------------------------------------------------
__global__ __launch_bounds__(512) void gemm_exp_sums(
    const unsigned char* __restrict__ xq, const unsigned char* __restrict__ yq,
    float* __restrict__ rowsum, float* __restrict__ colsum)
{
    __shared__ __align__(16) unsigned char LDS[2][32768];  // [buf][A:0-16K | B:16K-32K]

    const int t    = threadIdx.x;
    const int lane = t & 63;
    const int wave = t >> 6;        // 0..7
    const int q    = lane >> 4;
    const int l15  = lane & 15;

    const int R0 = blockIdx.y * 256;
    const int C0 = blockIdx.x * 256;
    const int wRow = (wave >> 2) * 64;   // 0 or 64 (second half at +128)
    const int wCol = (wave & 3) * 64;    // 0,64,128,192

    f32x4_t acc[2][4][4];
    #pragma unroll
    for (int hh = 0; hh < 2; hh++)
        #pragma unroll
        for (int i = 0; i < 4; i++)
            #pragma unroll
            for (int j = 0; j < 4; j++)
                acc[hh][i][j] = (f32x4_t){0.f, 0.f, 0.f, 0.f};

    // DMA sources: wave stages A panels {2w,2w+1}, B panels {2w,2w+1}.
    // fp4 panel stride 8192 B; (p,kb) chunk = 1 KB at p*8192 + kb*1024.
    const unsigned char* srcA =
        xq + (size_t)((R0 >> 4) + 2 * wave) * 8192 + lane * 16;
    const unsigned char* srcB =
        yq + (size_t)((C0 >> 4) + 2 * wave) * 8192 + lane * 16;

    const int sl = (q ^ (l15 & 3)) << 4;   // swizzled 16-B slot within row

    // one stage = 4 DMAs per wave
    auto issue = [&](int kb, int buf) {
        #pragma unroll
        for (int pp = 0; pp < 2; ++pp) {
            async16(srcA + pp * 8192 + kb * 1024,
                    &LDS[buf][(2 * wave + pp) * 1024]);
            async16(srcB + pp * 8192 + kb * 1024,
                    &LDS[buf][16384 + (2 * wave + pp) * 1024]);
        }
    };

    issue(0, 0);

    #pragma unroll 1
    for (int kb = 0; kb < 8; ++kb) {
        const int buf = kb & 1;
        if (kb < 7) {
            issue(kb + 1, buf ^ 1);
            __builtin_amdgcn_s_waitcnt(0xF74);   // vmcnt(4): prev stage's DMAs done
        } else {
            __builtin_amdgcn_s_waitcnt(0xF70);   // vmcnt(0): last stage
        }
        __builtin_amdgcn_s_barrier();

        i32x8_t bfr[4];
        #pragma unroll
        for (int nt = 0; nt < 4; ++nt) {
            const i32x4_t v = *reinterpret_cast<const i32x4_t*>(
                &LDS[buf][16384 + ((wCol >> 4) + nt) * 1024 + l15 * 64 + sl]);
            bfr[nt][0] = v[0]; bfr[nt][1] = v[1]; bfr[nt][2] = v[2]; bfr[nt][3] = v[3];
            bfr[nt][4] = 0;    bfr[nt][5] = 0;    bfr[nt][6] = 0;    bfr[nt][7] = 0;
        }
        #pragma unroll
        for (int hh = 0; hh < 2; ++hh) {
            #pragma unroll
            for (int mt = 0; mt < 4; ++mt) {
                const i32x4_t v = *reinterpret_cast<const i32x4_t*>(
                    &LDS[buf][((wRow >> 4) + hh * 8 + mt) * 1024 + l15 * 64 + sl]);
                i32x8_t af;
                af[0] = v[0]; af[1] = v[1]; af[2] = v[2]; af[3] = v[3];
                af[4] = 0;    af[5] = 0;    af[6] = 0;    af[7] = 0;
                #pragma unroll
                for (int nt = 0; nt < 4; ++nt)
                    acc[hh][mt][nt] = __builtin_amdgcn_mfma_scale_f32_16x16x128_f8f6f4(
                        af, bfr[nt], acc[hh][mt][nt],
                        4, 4,                       // cbsz=fp4(e2m1), blgp=fp4(e2m1)
                        0, 0x7F7F7F7F,              // A scales: E8M0 127 = 2^0
                        0, 0x7F7F7F7F);             // B scales: 2^0
            }
        }

        __builtin_amdgcn_s_barrier();  // reads of buf done before re-targeting
    }

    // Epilogue: acc holds 1024*S (32x32 pre-scale) -> E = exp2(acc/(1024*TAU*ln2)).
    const float kScale = (float)(1.0 / (1024.0 * 0.07 * 0.6931471805599453));
    float csum[4] = {0.f, 0.f, 0.f, 0.f};
    #pragma unroll
    for (int hh = 0; hh < 2; ++hh) {
        #pragma unroll
        for (int mt = 0; mt < 4; ++mt) {
            float rsum[4] = {0.f, 0.f, 0.f, 0.f};
            #pragma unroll
            for (int nt = 0; nt < 4; ++nt) {
                #pragma unroll
                for (int r = 0; r < 4; ++r) {
                    const float e = exp2f(acc[hh][mt][nt][r] * kScale);
                    rsum[r]  += e;
                    csum[nt] += e;
                }
            }
            #pragma unroll
            for (int r = 0; r < 4; ++r) {
                float v = rsum[r];
                v += __shfl_xor(v, 1, 64);
                v += __shfl_xor(v, 2, 64);
                v += __shfl_xor(v, 4, 64);
                v += __shfl_xor(v, 8, 64);
                if (l15 == 0)
                    atomicAdd(&rowsum[R0 + wRow + hh * 128 + mt * 16 + q * 4 + r], v);
            }
        }
    }
    #pragma unroll
    for (int nt = 0; nt < 4; ++nt) {
        float v = csum[nt];
        v += __shfl_xor(v, 16, 64);
        v += __shfl_xor(v, 32, 64);
        if (lane < 16)
            atomicAdd(&colsum[C0 + wCol + nt * 16 + l15], v);
    }
}

// ---------------------------------------------------------------------------
// Kernel 3: loss = -1/(2B) [ (2/TAU)*sum(sdiag) - sum(log(rowsum+extra))
//                            - sum(log(colsum+extra)) ]
// ---------------------------------------------------------------------------
__global__ __launch_bounds__(1024) void finalize(
    const float* __restrict__ rowsum, const float* __restrict__ colsum,
    const float* __restrict__ sdiag, float* __restrict__ out)
{
    const float extra = (float)(NB * 1e-6 + 1e-6);
    double local = 0.0;
    for (int i = threadIdx.x; i < NB; i += 1024) {
        local += (double)sdiag[i] * (2.0 / 0.07)
               - (double)logf(rowsum[i] + extra)
               - (double)logf(colsum[i] + extra);
    }
    #pragma unroll
    for (int off = 1; off < 64; off <<= 1)
        local += __shfl_xor(local, off, 64);
    __shared__ double dred[16];
    const int wave = threadIdx.x >> 6;
    if ((threadIdx.x & 63) == 0) dred[wave] = local;
    __syncthreads();
    if (threadIdx.x == 0) {
        double tot = 0.0;
        #pragma unroll
        for (int w = 0; w < 16; ++w) tot += dred[w];
        out[0] = (float)(tot * (-1.0 / (2.0 * NB)));
    }
}

// ---------------------------------------------------------------------------
extern "C" void kernel_launch(void* const* d_in, const int* in_sizes, int n_in,
                              void* d_out, int out_size, void* d_ws, size_t ws_size,
                              hipStream_t stream)
{
    const float* x = (const float*)d_in[0];
    const float* y = (const float*)d_in[1];
    float* out = (float*)d_out;

    char* ws = (char*)d_ws;
    unsigned char* xq = (unsigned char*)ws;                                 // 2 MB fp4 swizzled
    unsigned char* yq = (unsigned char*)(ws + (size_t)2 * 1024 * 1024);     // 2 MB fp4 swizzled
    float* rowsum = (float*)(ws + (size_t)8 * 1024 * 1024);                 // 16 KB
    float* colsum = rowsum + NB;                                            // 16 KB
    float* sdiag  = colsum + NB;                                            // 16 KB

    normalize_rows<<<NB / 4, 256, 0, stream>>>(x, y, xq, yq, sdiag, rowsum);

    dim3 grid(16, 16);
    gemm_exp_sums<<<grid, 512, 0, stream>>>(xq, yq, rowsum, colsum);

    finalize<<<1, 1024, 0, stream>>>(rowsum, colsum, sdiag, out);
}